// Round 2
// baseline (1222.616 us; speedup 1.0000x reference)
//
#include <hip/hip_runtime.h>

// ---------------- preprocessing kernels ----------------

__global__ void k_deg(const int* __restrict__ col, int* __restrict__ indeg, int E){
  int e = blockIdx.x*blockDim.x + threadIdx.x;
  if (e < E) atomicAdd(&indeg[col[e]], 1);
}

__global__ void k_dinv(const int* __restrict__ indeg, float* __restrict__ dinv, int n){
  int i = blockIdx.x*blockDim.x + threadIdx.x;
  if (i < n) dinv[i] = rsqrtf((float)(indeg[i] + 1));
}

__global__ __launch_bounds__(256) void k_scan1(const int* __restrict__ indeg, int* __restrict__ rp,
                                               int* __restrict__ bsums, int n){
  __shared__ int s[256];
  int b = blockIdx.x, t = threadIdx.x;
  int base = b*1024 + t*4;
  int v[4]; int tsum = 0;
  #pragma unroll
  for (int j=0;j<4;j++){ v[j] = (base+j < n) ? indeg[base+j] : 0; tsum += v[j]; }
  s[t] = tsum; __syncthreads();
  for (int d=1; d<256; d<<=1){ int x = (t>=d) ? s[t-d] : 0; __syncthreads(); s[t] += x; __syncthreads(); }
  int run = s[t] - tsum;
  if (t == 255) bsums[b] = s[255];
  #pragma unroll
  for (int j=0;j<4;j++){ if (base+j < n){ rp[base+j] = run; } run += v[j]; }
}

__global__ __launch_bounds__(128) void k_scan2(int* bsums, int* rp, int nb, int n){
  __shared__ int s[128];
  int t = threadIdx.x;
  int orig = (t < nb) ? bsums[t] : 0;
  s[t] = orig; __syncthreads();
  for (int d=1; d<128; d<<=1){ int x = (t>=d) ? s[t-d] : 0; __syncthreads(); s[t] += x; __syncthreads(); }
  if (t < nb) bsums[t] = s[t] - orig;
  if (t == 127) rp[n] = s[127];
}

__global__ void k_scan3(int* __restrict__ rp, int* __restrict__ nxt, const int* __restrict__ bsums, int n){
  int i = blockIdx.x*blockDim.x + threadIdx.x;
  if (i < n){ int v = rp[i] + bsums[i >> 10]; rp[i] = v; nxt[i] = v; }
}

__global__ void k_scatter(const int* __restrict__ row, const int* __restrict__ col,
                          int* __restrict__ nxt, int* __restrict__ csr, int E){
  int e = blockIdx.x*blockDim.x + threadIdx.x;
  if (e < E){ int c = col[e]; int p = atomicAdd(&nxt[c], 1); csr[p] = row[e]; }
}

// ---------------- sparse propagation: out = D^-1/2 (A+I) D^-1/2 h ----------------
// pull-based, one wave per node, lanes across features

template<int F>
__global__ __launch_bounds__(256) void k_prop(const float* __restrict__ h, const float* __restrict__ dinv,
                                              const int* __restrict__ rp, const int* __restrict__ csr,
                                              float* __restrict__ out, int n){
  int node = (int)((blockIdx.x*(long)blockDim.x + threadIdx.x) >> 6);
  int lane = threadIdx.x & 63;
  if (node >= n) return;
  constexpr int C = (F + 63) / 64;
  float di = dinv[node];
  float acc[C];
  #pragma unroll
  for (int c=0;c<C;c++){ int f=c*64+lane; acc[c] = (f < F) ? di * h[(size_t)node*F + f] : 0.0f; }
  int e0 = rp[node], e1 = rp[node+1];
  for (int e=e0; e<e1; ++e){
    int s = csr[e];
    float ds = dinv[s];
    const float* hs = h + (size_t)s*F;
    #pragma unroll
    for (int c=0;c<C;c++){ int f=c*64+lane; if (f < F) acc[c] += ds * hs[f]; }
  }
  #pragma unroll
  for (int c=0;c<C;c++){ int f=c*64+lane; if (f < F) out[(size_t)node*F + f] = di * acc[c]; }
}

// ---------------- tiled f32 GEMM: C = relu(A@W + b), optional fused max-pool ----------------
// 64x64 tile, 256 threads, 4x4 acc per thread

__global__ __launch_bounds__(256) void k_gemm64(
    const float* __restrict__ A, const float* __restrict__ W, const float* __restrict__ bias,
    float* __restrict__ Cout, const int* __restrict__ batch, unsigned* __restrict__ gpool,
    int n, int K, int NC, int relu, int pool, int G)
{
  __shared__ float As[64][65];
  __shared__ float Ws[64][68];   // 68: keeps float4 reads 16B-aligned
  __shared__ unsigned pmax[2][64];
  int r0 = blockIdx.x * 64, c0 = blockIdx.y * 64;
  int tid = threadIdx.x;
  int tx = tid & 15, ty = tid >> 4;
  float acc[4][4] = {{0.f,0.f,0.f,0.f},{0.f,0.f,0.f,0.f},{0.f,0.f,0.f,0.f},{0.f,0.f,0.f,0.f}};

  for (int k0 = 0; k0 < K; k0 += 64){
    int klen = (K - k0 < 64) ? (K - k0) : 64;
    #pragma unroll
    for (int j=0;j<16;j++){
      int idx = tid + 256*j;
      int r = idx >> 6, kk = idx & 63;
      As[r][kk] = (r0+r < n && kk < klen) ? A[(size_t)(r0+r)*K + (k0+kk)] : 0.0f;
      Ws[r][kk] = (r < klen && c0+kk < NC) ? W[(size_t)(k0+r)*NC + (c0+kk)] : 0.0f;
    }
    __syncthreads();
    #pragma unroll 4
    for (int kk=0; kk<klen; ++kk){
      float a0 = As[4*ty+0][kk], a1 = As[4*ty+1][kk], a2 = As[4*ty+2][kk], a3 = As[4*ty+3][kk];
      float4 w = *(const float4*)&Ws[kk][4*tx];
      acc[0][0] += a0*w.x; acc[0][1] += a0*w.y; acc[0][2] += a0*w.z; acc[0][3] += a0*w.w;
      acc[1][0] += a1*w.x; acc[1][1] += a1*w.y; acc[1][2] += a1*w.z; acc[1][3] += a1*w.w;
      acc[2][0] += a2*w.x; acc[2][1] += a2*w.y; acc[2][2] += a2*w.z; acc[2][3] += a2*w.w;
      acc[3][0] += a3*w.x; acc[3][1] += a3*w.y; acc[3][2] += a3*w.z; acc[3][3] += a3*w.w;
    }
    __syncthreads();
  }

  if (!pool){
    #pragma unroll
    for (int u=0;u<4;u++){
      int r = r0 + 4*ty + u;
      if (r < n){
        #pragma unroll
        for (int j=0;j<4;j++){
          int c = c0 + 4*tx + j;
          if (c < NC){
            float v = acc[u][j] + bias[c];
            if (relu) v = fmaxf(v, 0.0f);
            Cout[(size_t)r*NC + c] = v;
          }
        }
      }
    }
  } else {
    // fused relu + segment-max pool (batch sorted, graph size >= 64 -> <=2 graphs/tile)
    int g0 = batch[r0 < n ? r0 : (n-1)];
    if (tid < 128) pmax[tid>>6][tid&63] = 0u;
    __syncthreads();
    #pragma unroll
    for (int u=0;u<4;u++){
      int r = r0 + 4*ty + u;
      if (r < n){
        int gi = batch[r] - g0; if (gi > 1) gi = 1;
        #pragma unroll
        for (int j=0;j<4;j++){
          int c = c0 + 4*tx + j;
          if (c < NC){
            float v = acc[u][j] + bias[c];
            v = fmaxf(v, 0.0f);
            if (v > 0.0f) atomicMax(&pmax[gi][4*tx+j], __float_as_uint(v));
          }
        }
      }
    }
    __syncthreads();
    if (tid < 128){
      int gi = tid >> 6, c = tid & 63;
      unsigned v = pmax[gi][c];
      int gg = g0 + gi;
      if (v != 0u && (c0 + c) < NC && gg < G)
        atomicMax(&gpool[(size_t)gg*NC + (c0 + c)], v);
    }
  }
}

// ---------------- final MLP layer: out[row] = g2[row] @ Wg2 + bg2 ----------------

__global__ __launch_bounds__(128) void k_mlp2(const float* __restrict__ g2, const float* __restrict__ W,
                                              const float* __restrict__ b, float* __restrict__ out,
                                              int K, int NC){
  __shared__ float As[1024];
  int row = blockIdx.x; int tid = threadIdx.x;
  for (int k = tid; k < K; k += 128) As[k] = g2[(size_t)row*K + k];
  __syncthreads();
  float acc = 0.f;
  for (int k = 0; k < K; ++k) acc += As[k] * W[(size_t)k*NC + tid];
  out[(size_t)row*NC + tid] = acc + b[tid];
}

// ---------------- launcher ----------------

extern "C" void kernel_launch(void* const* d_in, const int* in_sizes, int n_in,
                              void* d_out, int out_size, void* d_ws, size_t ws_size,
                              hipStream_t stream)
{
  const float* x   = (const float*)d_in[0];
  const int*   ei  = (const int*)d_in[1];
  const int*   batch = (const int*)d_in[2];
  const float* W1  = (const float*)d_in[3]; const float* b1  = (const float*)d_in[4];
  const float* W2  = (const float*)d_in[5]; const float* b2  = (const float*)d_in[6];
  const float* W3  = (const float*)d_in[7]; const float* b3  = (const float*)d_in[8];
  const float* Wg1 = (const float*)d_in[9]; const float* bg1 = (const float*)d_in[10];
  const float* Wg2 = (const float*)d_in[11]; const float* bg2 = (const float*)d_in[12];
  float* out = (float*)d_out;

  const int F1 = 75;
  int n = in_sizes[0] / F1;          // 100000
  int E = in_sizes[1] / 2;           // 800000
  int G = out_size / 128;            // 512
  const int* row = ei;
  const int* col = ei + E;

  char* ws = (char*)d_ws;
  size_t off = 0;
  auto alloc = [&](size_t bytes){ size_t o = off; off += (bytes + 255) & ~(size_t)255; return o; };
  float* bufQ  = (float*)(ws + alloc((size_t)n*150*4));  // propagated features (<=150 wide)
  float* bufH1 = (float*)(ws + alloc((size_t)n*75*4));   // h1
  float* bufH2 = (float*)(ws + alloc((size_t)n*150*4));  // h2
  float* dinv  = (float*)(ws + alloc((size_t)n*4));
  int*   indeg = (int*)  (ws + alloc((size_t)n*4));
  int*   rp    = (int*)  (ws + alloc((size_t)(n+1)*4));
  int*   nxt   = (int*)  (ws + alloc((size_t)n*4));
  int*   csr   = (int*)  (ws + alloc((size_t)E*4));
  int*   bsums = (int*)  (ws + alloc(1024*4));
  unsigned* g  = (unsigned*)(ws + alloc((size_t)G*300*4));
  float* gh    = (float*)(ws + alloc((size_t)G*1024*4));

  hipMemsetAsync(indeg, 0, (size_t)n*4, stream);
  hipMemsetAsync(g, 0, (size_t)G*300*4, stream);

  k_deg<<<(E+255)/256, 256, 0, stream>>>(col, indeg, E);
  k_dinv<<<(n+255)/256, 256, 0, stream>>>(indeg, dinv, n);

  int nb = (n + 1023) / 1024;        // 98 <= 128
  k_scan1<<<nb, 256, 0, stream>>>(indeg, rp, bsums, n);
  k_scan2<<<1, 128, 0, stream>>>(bsums, rp, nb, n);
  k_scan3<<<(n+255)/256, 256, 0, stream>>>(rp, nxt, bsums, n);
  k_scatter<<<(E+255)/256, 256, 0, stream>>>(row, col, nxt, csr, E);

  int pb = (n + 3) / 4;              // 4 waves(nodes)/block

  // layer 1: q1 = Ahat x ; h1 = relu(q1@W1 + b1)
  k_prop<75><<<pb, 256, 0, stream>>>(x, dinv, rp, csr, bufQ, n);
  {
    dim3 grid((n+63)/64, (75+63)/64);
    k_gemm64<<<grid, 256, 0, stream>>>(bufQ, W1, b1, bufH1, nullptr, nullptr, n, 75, 75, 1, 0, G);
  }
  // layer 2
  k_prop<75><<<pb, 256, 0, stream>>>(bufH1, dinv, rp, csr, bufQ, n);
  {
    dim3 grid((n+63)/64, (150+63)/64);
    k_gemm64<<<grid, 256, 0, stream>>>(bufQ, W2, b2, bufH2, nullptr, nullptr, n, 75, 150, 1, 0, G);
  }
  // layer 3 + fused relu + segment-max pool into g
  k_prop<150><<<pb, 256, 0, stream>>>(bufH2, dinv, rp, csr, bufQ, n);
  {
    dim3 grid((n+63)/64, (300+63)/64);
    k_gemm64<<<grid, 256, 0, stream>>>(bufQ, W3, b3, nullptr, batch, g, n, 150, 300, 1, 1, G);
  }
  // MLP head
  {
    dim3 grid((G+63)/64, (1024+63)/64);
    k_gemm64<<<grid, 256, 0, stream>>>((const float*)g, Wg1, bg1, gh, nullptr, nullptr, G, 300, 1024, 1, 0, G);
  }
  k_mlp2<<<G, 128, 0, stream>>>(gh, Wg2, bg2, out, 1024, 128);
}